// Round 1
// baseline (106.052 us; speedup 1.0000x reference)
//
#include <hip/hip_runtime.h>
#include <math.h>

#define BATCH 4
#define NPTS 8192
#define TB 256              // threads per block (hd_partial)
#define TN 8                // n-points per thread (register-blocked)
#define NT (TB * TN)        // 2048 n per block
#define NTILES (NPTS / NT)  // 4
#define MCH 16              // m-chunks
#define MC (NPTS / MCH)     // 512 m per chunk
#define SL 16               // n-slices in the reduce kernel

// ws layout: unsigned minbits[2][BATCH][NPTS]  (256 KB)  then unsigned maxbits[BATCH]

__global__ __launch_bounds__(256) void hd_init(unsigned* __restrict__ minbits,
                                               unsigned* __restrict__ maxbits) {
    int i = blockIdx.x * 256 + threadIdx.x;
    if (i < 2 * BATCH * NPTS) minbits[i] = 0x7F800000u;  // +inf bits
    if (i < BATCH) maxbits[i] = 0u;
}

// One directed pass chunk: for each of NT x-points, min over an MC-chunk of y.
// d^2 = |x|^2 + |y|^2 - 2 x.y  computed as  (a3 + y.w) + a0*y0 + a1*y1 + a2*y2
// with a = (-2x0, -2x1, -2x2, |x|^2):  1 add + 3 fma per pair.
__global__ __launch_bounds__(TB) void hd_partial(const float* __restrict__ pred,
                                                 const float* __restrict__ gt,
                                                 unsigned* __restrict__ minbits) {
    const int tid = threadIdx.x;
    const int ntile = blockIdx.x / MCH;
    const int mc = blockIdx.x % MCH;
    const int b = blockIdx.y;
    const int dir = blockIdx.z;

    const float* X = (dir == 0) ? pred + (size_t)b * NPTS * 3 : gt + (size_t)b * NPTS * 3;
    const float* Y = (dir == 0) ? gt + (size_t)b * NPTS * 3 : pred + (size_t)b * NPTS * 3;

    __shared__ float4 tile[MC];  // (y0, y1, y2, |y|^2) — 8 KB
    for (int i = tid; i < MC; i += TB) {
        int m = mc * MC + i;
        float y0 = Y[3 * m], y1 = Y[3 * m + 1], y2 = Y[3 * m + 2];
        tile[i] = make_float4(y0, y1, y2, y0 * y0 + y1 * y1 + y2 * y2);
    }

    float a0[TN], a1[TN], a2[TN], a3[TN], rmin[TN];
    const int nbase = ntile * NT;
#pragma unroll
    for (int k = 0; k < TN; ++k) {
        int n = nbase + k * TB + tid;
        float x0 = X[3 * n], x1 = X[3 * n + 1], x2 = X[3 * n + 2];
        a0[k] = -2.f * x0;
        a1[k] = -2.f * x1;
        a2[k] = -2.f * x2;
        a3[k] = x0 * x0 + x1 * x1 + x2 * x2;
        rmin[k] = 3.4e38f;
    }
    __syncthreads();

#pragma unroll 2
    for (int m = 0; m < MC; m += 2) {
        float4 ya = tile[m];
        float4 yb = tile[m + 1];
#pragma unroll
        for (int k = 0; k < TN; ++k) {
            float da = fmaf(a0[k], ya.x, a3[k] + ya.w);
            da = fmaf(a1[k], ya.y, da);
            da = fmaf(a2[k], ya.z, da);
            float db = fmaf(a0[k], yb.x, a3[k] + yb.w);
            db = fmaf(a1[k], yb.y, db);
            db = fmaf(a2[k], yb.z, db);
            rmin[k] = fminf(rmin[k], fminf(da, db));  // -> v_min3_f32
        }
    }

    unsigned* mb = minbits + ((size_t)(dir * BATCH + b)) * NPTS + nbase;
#pragma unroll
    for (int k = 0; k < TN; ++k) {
        float v = fmaxf(rmin[k], 0.f);  // clamp tiny negative d^2 from cancellation
        atomicMin(&mb[k * TB + tid], __float_as_uint(v));
    }
}

// max over n (and dir, since final = max of both directed maxima) per batch.
__global__ __launch_bounds__(256) void hd_reduce(const unsigned* __restrict__ minbits,
                                                 unsigned* __restrict__ maxbits) {
    const int tid = threadIdx.x;
    const int slice = blockIdx.x;
    const int b = blockIdx.y;
    const int dir = blockIdx.z;
    const unsigned* mb = minbits + ((size_t)(dir * BATCH + b)) * NPTS + slice * (NPTS / SL);
    unsigned vmax = 0u;
    for (int i = tid; i < NPTS / SL; i += 256) {
        unsigned v = mb[i];
        vmax = v > vmax ? v : vmax;
    }
    __shared__ unsigned sm[256];
    sm[tid] = vmax;
    __syncthreads();
    for (int s = 128; s > 0; s >>= 1) {
        if (tid < s) sm[tid] = sm[tid + s] > sm[tid] ? sm[tid + s] : sm[tid];
        __syncthreads();
    }
    if (tid == 0) atomicMax(&maxbits[b], sm[0]);
}

__global__ void hd_final(const unsigned* __restrict__ maxbits, float* __restrict__ out) {
    int b = threadIdx.x;
    if (b < BATCH) out[b] = sqrtf(__uint_as_float(maxbits[b]));
}

extern "C" void kernel_launch(void* const* d_in, const int* in_sizes, int n_in,
                              void* d_out, int out_size, void* d_ws, size_t ws_size,
                              hipStream_t stream) {
    const float* pred = (const float*)d_in[0];  // [B, N, 3]
    const float* gt = (const float*)d_in[1];    // [B, M, 3]
    unsigned* minbits = (unsigned*)d_ws;
    unsigned* maxbits = minbits + 2 * BATCH * NPTS;

    hd_init<<<(2 * BATCH * NPTS + 255) / 256, 256, 0, stream>>>(minbits, maxbits);
    hd_partial<<<dim3(NTILES * MCH, BATCH, 2), TB, 0, stream>>>(pred, gt, minbits);
    hd_reduce<<<dim3(SL, BATCH, 2), 256, 0, stream>>>(minbits, maxbits);
    hd_final<<<1, 64, 0, stream>>>(maxbits, (float*)d_out);
}

// Round 2
// 99.613 us; speedup vs baseline: 1.0646x; 1.0646x over previous
//
#include <hip/hip_runtime.h>
#include <math.h>

#define BATCH 4
#define NPTS 8192
#define TB 256              // threads per block (hd_partial)
#define TN 8                // n-points per thread (register-blocked)
#define NT (TB * TN)        // 2048 n per block
#define NTILES (NPTS / NT)  // 4
#define MCH 64              // m-chunks -> grid 4*64*4*2 = 2048 blocks (~8/CU)
#define MC (NPTS / MCH)     // 128 m per chunk

// ws layout: unsigned minbits[2][BATCH][NPTS]  (256 KB)

__global__ __launch_bounds__(256) void hd_init(uint4* __restrict__ minbits) {
    // 2*BATCH*NPTS = 64K uints = 16K uint4 = 64 blocks * 256 threads exactly
    int i = blockIdx.x * 256 + threadIdx.x;
    minbits[i] = make_uint4(0x7F800000u, 0x7F800000u, 0x7F800000u, 0x7F800000u);
}

// Directed pass chunk. For fixed x:  min_m d^2 = x^2 + min_m (y^2 - 2 x.y),
// so the inner loop computes e = y2 + a0*y0 + a1*y1 + a2*y2 with
// a = -2x and y2 folded in as the FMA seed: 3 fma per pair, +0.5 min3.
__global__ __launch_bounds__(TB) void hd_partial(const float* __restrict__ pred,
                                                 const float* __restrict__ gt,
                                                 unsigned* __restrict__ minbits) {
    const int tid = threadIdx.x;
    const int ntile = blockIdx.x / MCH;
    const int mc = blockIdx.x % MCH;
    const int b = blockIdx.y;
    const int dir = blockIdx.z;

    const float* X = (dir == 0) ? pred + (size_t)b * NPTS * 3 : gt + (size_t)b * NPTS * 3;
    const float* Y = (dir == 0) ? gt + (size_t)b * NPTS * 3 : pred + (size_t)b * NPTS * 3;

    __shared__ float4 tile[MC];  // (y0, y1, y2, |y|^2) — 2 KB
    if (tid < MC) {
        int m = mc * MC + tid;
        float y0 = Y[3 * m], y1 = Y[3 * m + 1], y2 = Y[3 * m + 2];
        tile[tid] = make_float4(y0, y1, y2, y0 * y0 + y1 * y1 + y2 * y2);
    }

    float a0[TN], a1[TN], a2[TN], a3[TN], rmin[TN];
    const int nbase = ntile * NT;
#pragma unroll
    for (int k = 0; k < TN; ++k) {
        int n = nbase + k * TB + tid;
        float x0 = X[3 * n], x1 = X[3 * n + 1], x2 = X[3 * n + 2];
        a0[k] = -2.f * x0;
        a1[k] = -2.f * x1;
        a2[k] = -2.f * x2;
        a3[k] = x0 * x0 + x1 * x1 + x2 * x2;   // added AFTER the inner loop
        rmin[k] = 3.4e38f;
    }
    __syncthreads();

    for (int m = 0; m < MC; m += 4) {
        float4 ya = tile[m];
        float4 yb = tile[m + 1];
        float4 yc = tile[m + 2];
        float4 yd = tile[m + 3];
#pragma unroll
        for (int k = 0; k < TN; ++k) {
            float ea = fmaf(a0[k], ya.x, ya.w);
            ea = fmaf(a1[k], ya.y, ea);
            ea = fmaf(a2[k], ya.z, ea);
            float eb = fmaf(a0[k], yb.x, yb.w);
            eb = fmaf(a1[k], yb.y, eb);
            eb = fmaf(a2[k], yb.z, eb);
            rmin[k] = fminf(fminf(ea, eb), rmin[k]);   // v_min3_f32
            float ec = fmaf(a0[k], yc.x, yc.w);
            ec = fmaf(a1[k], yc.y, ec);
            ec = fmaf(a2[k], yc.z, ec);
            float ed = fmaf(a0[k], yd.x, yd.w);
            ed = fmaf(a1[k], yd.y, ed);
            ed = fmaf(a2[k], yd.z, ed);
            rmin[k] = fminf(fminf(ec, ed), rmin[k]);   // v_min3_f32
        }
    }

    unsigned* mb = minbits + ((size_t)(dir * BATCH + b)) * NPTS + nbase;
#pragma unroll
    for (int k = 0; k < TN; ++k) {
        float v = fmaxf(a3[k] + rmin[k], 0.f);  // add back x^2, clamp cancellation
        atomicMin(&mb[k * TB + tid], __float_as_uint(v));
    }
}

// One block per batch: max over both directions and all n, then sqrt -> out.
__global__ __launch_bounds__(256) void hd_reduce(const unsigned* __restrict__ minbits,
                                                 float* __restrict__ out) {
    const int tid = threadIdx.x;
    const int b = blockIdx.x;
    const uint4* p0 = (const uint4*)(minbits + (size_t)b * NPTS);            // dir 0
    const uint4* p1 = (const uint4*)(minbits + (size_t)(BATCH + b) * NPTS);  // dir 1
    unsigned vmax = 0u;
    for (int i = tid; i < NPTS / 4; i += 256) {
        uint4 u = p0[i];
        uint4 v = p1[i];
        unsigned a = max(max(u.x, u.y), max(u.z, u.w));
        unsigned c = max(max(v.x, v.y), max(v.z, v.w));
        unsigned d = max(a, c);
        vmax = max(vmax, d);
    }
    __shared__ unsigned sm[256];
    sm[tid] = vmax;
    __syncthreads();
    for (int s = 128; s > 0; s >>= 1) {
        if (tid < s) sm[tid] = max(sm[tid], sm[tid + s]);
        __syncthreads();
    }
    if (tid == 0) out[b] = sqrtf(__uint_as_float(sm[0]));
}

extern "C" void kernel_launch(void* const* d_in, const int* in_sizes, int n_in,
                              void* d_out, int out_size, void* d_ws, size_t ws_size,
                              hipStream_t stream) {
    const float* pred = (const float*)d_in[0];  // [B, N, 3]
    const float* gt = (const float*)d_in[1];    // [B, M, 3]
    unsigned* minbits = (unsigned*)d_ws;

    hd_init<<<(2 * BATCH * NPTS / 4 + 255) / 256, 256, 0, stream>>>((uint4*)minbits);
    hd_partial<<<dim3(NTILES * MCH, BATCH, 2), TB, 0, stream>>>(pred, gt, minbits);
    hd_reduce<<<BATCH, 256, 0, stream>>>(minbits, (float*)d_out);
}